// Round 5
// baseline (360.207 us; speedup 1.0000x reference)
//
#include <hip/hip_runtime.h>
#include <hip/hip_fp16.h>

#define SLOPE 0.2f

__device__ __forceinline__ float lrelu(float v) { return v >= 0.f ? v : SLOPE * v; }

__device__ __forceinline__ unsigned pack2(float a, float b) {
    __half2 h = __floats2half2_rn(a, b);
    return *reinterpret_cast<unsigned*>(&h);
}
__device__ __forceinline__ float2 h2f(unsigned u) {
    __half2 h = *reinterpret_cast<__half2*>(&u);
    return __half22float2(h);
}

// 8 half elements (uint4) scaled by f32 'a', accumulated into 8 f32 lanes.
// v_fma_mix_f32 folds the f16->f32 convert into the FMA.
__device__ __forceinline__ void mix8(float4& A, float4& B, float a, uint4 u) {
    asm("v_fma_mix_f32 %0, %8, %12, %0 op_sel:[0,0,0] op_sel_hi:[1,0,0]\n\t"
        "v_fma_mix_f32 %1, %8, %12, %1 op_sel:[1,0,0] op_sel_hi:[1,0,0]\n\t"
        "v_fma_mix_f32 %2, %9, %12, %2 op_sel:[0,0,0] op_sel_hi:[1,0,0]\n\t"
        "v_fma_mix_f32 %3, %9, %12, %3 op_sel:[1,0,0] op_sel_hi:[1,0,0]\n\t"
        "v_fma_mix_f32 %4, %10, %12, %4 op_sel:[0,0,0] op_sel_hi:[1,0,0]\n\t"
        "v_fma_mix_f32 %5, %10, %12, %5 op_sel:[1,0,0] op_sel_hi:[1,0,0]\n\t"
        "v_fma_mix_f32 %6, %11, %12, %6 op_sel:[0,0,0] op_sel_hi:[1,0,0]\n\t"
        "v_fma_mix_f32 %7, %11, %12, %7 op_sel:[1,0,0] op_sel_hi:[1,0,0]"
        : "+v"(A.x), "+v"(A.y), "+v"(A.z), "+v"(A.w),
          "+v"(B.x), "+v"(B.y), "+v"(B.z), "+v"(B.w)
        : "v"(u.x), "v"(u.y), "v"(u.z), "v"(u.w), "v"(a));
}

// ============================================================================
// xp = h @ W (64 -> 128 = 2 heads * 64) + attention dots, block-tile GEMM.
// Input h is fp16 (written by k_ag). 64 nodes/block, 256 threads.
// ============================================================================
__global__ __launch_bounds__(256)
void k_xp_gemm64h(const __half* __restrict__ x, const float* __restrict__ W,
                  const float* __restrict__ as_, const float* __restrict__ ad_,
                  __half* __restrict__ xph, float* __restrict__ asrc,
                  float* __restrict__ adst, int N) {
    constexpr int K = 64;
    constexpr int ZS = K + 1;
    __shared__ float zs[64 * ZS];
    __shared__ float ws[K * 128];
    const int n0 = blockIdx.x * 64;
    const int t = threadIdx.x;

    for (int i = t; i < K * 32; i += 256) ((float4*)ws)[i] = ((const float4*)W)[i];
    for (int i = t; i < 64 * 8; i += 256) {          // 8 x uint4 (8 halfs) per row
        int n = i >> 3, k8 = i & 7;
        int gn = n0 + n;
        uint4 v = make_uint4(0u, 0u, 0u, 0u);
        if (gn < N) v = ((const uint4*)x)[(size_t)gn * 8 + k8];
        float2 f0 = h2f(v.x), f1 = h2f(v.y), f2 = h2f(v.z), f3 = h2f(v.w);
        float* zr = zs + n * ZS + k8 * 8;
        zr[0] = f0.x; zr[1] = f0.y; zr[2] = f1.x; zr[3] = f1.y;
        zr[4] = f2.x; zr[5] = f2.y; zr[6] = f3.x; zr[7] = f3.y;
    }
    __syncthreads();

    const int tx = t & 15, ty = t >> 4;
    const int c0a = tx * 4;
    const int c0b = 64 + tx * 4;

    float4 asA = *(const float4*)(as_ + c0a);
    float4 asB = *(const float4*)(as_ + c0b);
    float4 adA = *(const float4*)(ad_ + c0a);
    float4 adB = *(const float4*)(ad_ + c0b);

    float acc[4][8];
    #pragma unroll
    for (int i = 0; i < 4; ++i)
        #pragma unroll
        for (int j = 0; j < 8; ++j) acc[i][j] = 0.f;

    for (int k = 0; k < K; ++k) {
        float4 w0 = *(const float4*)(ws + k * 128 + c0a);
        float4 w1 = *(const float4*)(ws + k * 128 + c0b);
        #pragma unroll
        for (int i = 0; i < 4; ++i) {
            float zv = zs[(ty * 4 + i) * ZS + k];
            acc[i][0] += zv * w0.x; acc[i][1] += zv * w0.y;
            acc[i][2] += zv * w0.z; acc[i][3] += zv * w0.w;
            acc[i][4] += zv * w1.x; acc[i][5] += zv * w1.y;
            acc[i][6] += zv * w1.z; acc[i][7] += zv * w1.w;
        }
    }

    #pragma unroll
    for (int i = 0; i < 4; ++i) {
        int nl = ty * 4 + i, gn = n0 + nl;
        if (gn < N) {
            uint2 ua, ub;
            ua.x = pack2(acc[i][0], acc[i][1]);
            ua.y = pack2(acc[i][2], acc[i][3]);
            ub.x = pack2(acc[i][4], acc[i][5]);
            ub.y = pack2(acc[i][6], acc[i][7]);
            *(uint2*)(xph + (size_t)gn * 128 + c0a) = ua;
            *(uint2*)(xph + (size_t)gn * 128 + c0b) = ub;
        }
        float ps0 = acc[i][0]*asA.x + acc[i][1]*asA.y + acc[i][2]*asA.z + acc[i][3]*asA.w;
        float ps1 = acc[i][4]*asB.x + acc[i][5]*asB.y + acc[i][6]*asB.z + acc[i][7]*asB.w;
        float pd0 = acc[i][0]*adA.x + acc[i][1]*adA.y + acc[i][2]*adA.z + acc[i][3]*adA.w;
        float pd1 = acc[i][4]*adB.x + acc[i][5]*adB.y + acc[i][6]*adB.z + acc[i][7]*adB.w;
        #pragma unroll
        for (int off = 1; off <= 8; off <<= 1) {
            ps0 += __shfl_xor(ps0, off, 64);
            ps1 += __shfl_xor(ps1, off, 64);
            pd0 += __shfl_xor(pd0, off, 64);
            pd1 += __shfl_xor(pd1, off, 64);
        }
        if (tx == 0 && gn < N) {
            asrc[gn * 2]     = ps0;
            asrc[gn * 2 + 1] = ps1;
            adst[gn * 2]     = pd0;
            adst[gn * 2 + 1] = pd1;
        }
    }
}

// ============================================================================
// Scan kernels. scan_final also clones rowptr into 'cur' (scatter cursors).
// ============================================================================
__global__ void k_scan_partial(const int* __restrict__ deg, int* __restrict__ partial, int N) {
    int b = blockIdx.x, t = threadIdx.x;
    int base = b * 1024 + t * 4;
    int s = 0;
    for (int i = 0; i < 4; ++i) { int idx = base + i; if (idx < N) s += deg[idx]; }
    __shared__ int sh[256];
    sh[t] = s; __syncthreads();
    for (int off = 128; off > 0; off >>= 1) { if (t < off) sh[t] += sh[t + off]; __syncthreads(); }
    if (t == 0) partial[b] = sh[0];
}

__global__ void k_scan_final(const int* __restrict__ deg, const int* __restrict__ partial,
                             int* __restrict__ rowptr, int* __restrict__ cur,
                             int N, int E, int nb) {
    int b = blockIdx.x, t = threadIdx.x;
    __shared__ int shp[256];
    shp[t] = (t < nb) ? partial[t] : 0;
    __syncthreads();
    for (int off = 1; off < 256; off <<= 1) {
        int v = (t >= off) ? shp[t - off] : 0;
        __syncthreads();
        shp[t] += v;
        __syncthreads();
    }
    int pbase = (b > 0) ? shp[b - 1] : 0;
    __syncthreads();

    int base = b * 1024 + t * 4;
    int local[4]; int s = 0;
    for (int i = 0; i < 4; ++i) { int idx = base + i; local[i] = (idx < N) ? deg[idx] : 0; s += local[i]; }
    __shared__ int sh[256];
    int orig = s;
    sh[t] = s; __syncthreads();
    for (int off = 1; off < 256; off <<= 1) {
        int v = (t >= off) ? sh[t - off] : 0;
        __syncthreads();
        sh[t] += v;
        __syncthreads();
    }
    int run = pbase + sh[t] - orig;
    for (int i = 0; i < 4; ++i) {
        int idx = base + i;
        if (idx < N) { rowptr[idx] = run; cur[idx] = run; }
        run += local[i];
    }
    if (b == 0 && t == 0) rowptr[N] = E;
}

// ============================================================================
// Cursor-based scatter: pos = atomicAdd(cur[d]) -> csr_src[pos] = src.
// Replaces rank[] (saves 4MB write in hist + 4MB read here).
// ============================================================================
__global__ void k_scatter_cur(const int* __restrict__ src, const int* __restrict__ dst,
                              int* __restrict__ cur, int* __restrict__ csr_src, int E) {
    int e = blockIdx.x * blockDim.x + threadIdx.x;
    if (e >= E) return;
    int d = dst[e];
    int pos = atomicAdd(&cur[d], 1);
    csr_src[pos] = src[e];
}

// ============================================================================
// FUSED pre-work, branched on blockIdx range (all mutually independent):
//   [0, nTile)        -> xp_gemm K=6 (layer-1 projection)  [compute-first]
//   [nTile, +nEdge)   -> degree histogram (non-returning atomics)
//   [.., +nClimber)   -> climber embed + cpre
// R18: hist overlapped with gemm6 compute (its atomic latency hides under
// the projection GEMM instead of serializing the stream).
// ============================================================================
__global__ __launch_bounds__(256)
void k_pre(const float* __restrict__ x, const float* __restrict__ W1,
           const float* __restrict__ as1, const float* __restrict__ ad1,
           __half* __restrict__ xph, float* __restrict__ asrc,
           float* __restrict__ adst, int N,
           const int* __restrict__ dstI, int* __restrict__ deg, int E,
           const float* __restrict__ climber, const float* __restrict__ Wc,
           const float* __restrict__ bc, const float* __restrict__ Wm1,
           const float* __restrict__ bm1, float* __restrict__ cpre, int G,
           int nTile, int nEdgeBlk) {
    __shared__ float smem[4352];        // max(climber 4352, gemm6 1216) floats
    int bid = blockIdx.x;
    const int t = threadIdx.x;

    if (bid < nTile) {
        // ---- xp_gemm K=6 ----
        constexpr int K = 6, ZS = 7;
        float* zs = smem;               // 64*7  = 448
        float* ws = smem + 448;         // 6*128 = 768 (offset 1792 B, 16B-aligned)
        const int n0 = bid * 64;

        for (int i = t; i < K * 32; i += 256) ((float4*)ws)[i] = ((const float4*)W1)[i];
        for (int i = t; i < 64 * K; i += 256) {
            int n = i / K, k = i - n * K;
            int gn = n0 + n;
            zs[n * ZS + k] = (gn < N) ? x[(size_t)gn * K + k] : 0.f;
        }
        __syncthreads();

        const int tx = t & 15, ty = t >> 4;
        const int c0a = tx * 4;
        const int c0b = 64 + tx * 4;

        float4 asA = *(const float4*)(as1 + c0a);
        float4 asB = *(const float4*)(as1 + c0b);
        float4 adA = *(const float4*)(ad1 + c0a);
        float4 adB = *(const float4*)(ad1 + c0b);

        float acc[4][8];
        #pragma unroll
        for (int i = 0; i < 4; ++i)
            #pragma unroll
            for (int j = 0; j < 8; ++j) acc[i][j] = 0.f;

        for (int k = 0; k < K; ++k) {
            float4 w0 = *(const float4*)(ws + k * 128 + c0a);
            float4 w1 = *(const float4*)(ws + k * 128 + c0b);
            #pragma unroll
            for (int i = 0; i < 4; ++i) {
                float zv = zs[(ty * 4 + i) * ZS + k];
                acc[i][0] += zv * w0.x; acc[i][1] += zv * w0.y;
                acc[i][2] += zv * w0.z; acc[i][3] += zv * w0.w;
                acc[i][4] += zv * w1.x; acc[i][5] += zv * w1.y;
                acc[i][6] += zv * w1.z; acc[i][7] += zv * w1.w;
            }
        }

        #pragma unroll
        for (int i = 0; i < 4; ++i) {
            int nl = ty * 4 + i, gn = n0 + nl;
            if (gn < N) {
                uint2 ua, ub;
                ua.x = pack2(acc[i][0], acc[i][1]);
                ua.y = pack2(acc[i][2], acc[i][3]);
                ub.x = pack2(acc[i][4], acc[i][5]);
                ub.y = pack2(acc[i][6], acc[i][7]);
                *(uint2*)(xph + (size_t)gn * 128 + c0a) = ua;
                *(uint2*)(xph + (size_t)gn * 128 + c0b) = ub;
            }
            float ps0 = acc[i][0]*asA.x + acc[i][1]*asA.y + acc[i][2]*asA.z + acc[i][3]*asA.w;
            float ps1 = acc[i][4]*asB.x + acc[i][5]*asB.y + acc[i][6]*asB.z + acc[i][7]*asB.w;
            float pd0 = acc[i][0]*adA.x + acc[i][1]*adA.y + acc[i][2]*adA.z + acc[i][3]*adA.w;
            float pd1 = acc[i][4]*adB.x + acc[i][5]*adB.y + acc[i][6]*adB.z + acc[i][7]*adB.w;
            #pragma unroll
            for (int off = 1; off <= 8; off <<= 1) {
                ps0 += __shfl_xor(ps0, off, 64);
                ps1 += __shfl_xor(ps1, off, 64);
                pd0 += __shfl_xor(pd0, off, 64);
                pd1 += __shfl_xor(pd1, off, 64);
            }
            if (tx == 0 && gn < N) {
                asrc[gn * 2]     = ps0;
                asrc[gn * 2 + 1] = ps1;
                adst[gn * 2]     = pd0;
                adst[gn * 2 + 1] = pd1;
            }
        }
        return;
    }
    bid -= nTile;
    if (bid < nEdgeBlk) {
        // ---- degree histogram (no rank capture needed) ----
        int e = bid * 256 + t;
        if (e < E) atomicAdd(&deg[dstI[e]], 1);
        return;
    }
    bid -= nEdgeBlk;
    {
        // ---- climber embed + cpre ----
        float* ce   = smem;             // 4*64
        float* wm1b = smem + 256;       // 64*64
        for (int i = t; i < 1024; i += 256) ((float4*)wm1b)[i] = ((const float4*)Wm1)[1024 + i];
        int gl = t >> 6, c = t & 63;
        int g = bid * 4 + gl;
        float acc = bc[c];
        if (g < G)
            for (int k = 0; k < 4; ++k) acc += climber[g * 4 + k] * Wc[k * 64 + c];
        ce[gl * 64 + c] = fmaxf(acc, 0.f);
        __syncthreads();
        float o = bm1[c];
        for (int k = 0; k < 64; ++k) o += ce[gl * 64 + k] * wm1b[k * 64 + c];
        if (g < G) cpre[(size_t)g * 64 + c] = o;
    }
}

// ============================================================================
// FUSED softmax + gather (R1 structure — strided node walk, known-good):
// v_fma_mix gathers, 4-slot uniform tail, deferred normalization, fp16 out.
// NOTE (R14): do NOT fuse the classifier MLP in here (occupancy collapse).
// NOTE (R16): do NOT switch to contiguous chunks + deep pipeline (56->76us).
// NOTE (R4): write-byte cuts don't speed this kernel; it is gather/issue-bound.
// ============================================================================
__global__ void k_ag(const int* __restrict__ rowptr, const int* __restrict__ csr_src,
                     const float* __restrict__ asrc, const float* __restrict__ adst,
                     const __half* __restrict__ xph, const float* __restrict__ b,
                     __half* __restrict__ hout, int N) {
    int tid = blockIdx.x * blockDim.x + threadIdx.x;
    int lane = threadIdx.x & 63;
    int wid = tid >> 6;
    int nw = (gridDim.x * blockDim.x) >> 6;
    const int l  = lane & 31;
    const int hh = lane >> 5;
    const int g4 = (lane >> 3) & 3;
    const int c8 = lane & 7;
    const int lofs = hh * 8 + c8;
    const uint4* xp4 = (const uint4*)xph;
    float4 bb0 = ((const float4*)b)[c8 * 2];
    float4 bb1 = ((const float4*)b)[c8 * 2 + 1];

    for (int n = wid; n < N; n += nw) {
        int rs = rowptr[n], re = rowptr[n + 1], cnt = re - rs;
        uint4 uself = xp4[(size_t)n * 16 + lofs];       // issue early; 2 lines/wave
        float a_dst = adst[n * 2 + hh];
        float eself = __expf(lrelu(asrc[n * 2 + hh] + a_dst));

        float4 accA = make_float4(0.f, 0.f, 0.f, 0.f);
        float4 accB = make_float4(0.f, 0.f, 0.f, 0.f);
        float den;

        if (cnt <= 32) {
            float ev = 0.f; int s_reg = n;
            if (l < cnt) {
                s_reg = csr_src[rs + l];
                ev = __expf(lrelu(asrc[s_reg * 2 + hh] + a_dst));
            }
            if (g4 == 0) mix8(accA, accB, eself, uself);

            const int base = (hh << 5) - rs;
            int e0 = rs;
            for (; e0 + 4 < re; e0 += 8) {
                int ea = e0 + g4, eb = e0 + 4 + g4;
                float aa = __shfl(ev,    base + ea, 64);   // ea < re guaranteed
                int   sa = __shfl(s_reg, base + ea, 64);
                float ab = __shfl(ev,    base + eb, 64);
                int   sb = __shfl(s_reg, base + eb, 64);
                if (eb >= re) { ab = 0.f; sb = n; }
                uint4 u1 = xp4[(size_t)sa * 16 + lofs];
                uint4 u2 = xp4[(size_t)sb * 16 + lofs];
                mix8(accA, accB, aa, u1);
                mix8(accA, accB, ab, u2);
            }
            if (e0 < re) {                                  // wave-uniform 4-slot tail
                int ea = e0 + g4;
                float aa = __shfl(ev,    base + ea, 64);
                int   sa = __shfl(s_reg, base + ea, 64);
                if (ea >= re) { aa = 0.f; sa = n; }
                uint4 u1 = xp4[(size_t)sa * 16 + lofs];
                mix8(accA, accB, aa, u1);
            }
            // den reduce after gathers: shfls (LDS pipe) overlap vmcnt waits
            den = ev + (l == 0 ? eself : 0.f);
            #pragma unroll
            for (int off = 16; off > 0; off >>= 1) den += __shfl_xor(den, off, 64);
        } else {
            den = (l == 0) ? eself : 0.f;
            for (int e = rs + l; e < re; e += 32)
                den += __expf(lrelu(asrc[csr_src[e] * 2 + hh] + a_dst));
            #pragma unroll
            for (int off = 16; off > 0; off >>= 1) den += __shfl_xor(den, off, 64);
            if (g4 == 0) mix8(accA, accB, eself, uself);
            for (int e0 = rs; e0 < re; e0 += 8) {
                int ea = e0 + g4, eb = e0 + 4 + g4;
                bool va = ea < re, vb = eb < re;
                int sa = va ? csr_src[ea] : n;
                int sb = vb ? csr_src[eb] : n;
                float aa = va ? __expf(lrelu(asrc[sa * 2 + hh] + a_dst)) : 0.f;
                float ab = vb ? __expf(lrelu(asrc[sb * 2 + hh] + a_dst)) : 0.f;
                uint4 u1 = xp4[(size_t)sa * 16 + lofs];
                uint4 u2 = xp4[(size_t)sb * 16 + lofs];
                mix8(accA, accB, aa, u1);
                mix8(accA, accB, ab, u2);
            }
        }

        float inv = 1.f / (den + 1e-16f);

        // slot-group reduce (within head)
        #pragma unroll
        for (int off = 8; off <= 16; off <<= 1) {
            accA.x += __shfl_xor(accA.x, off, 64);
            accA.y += __shfl_xor(accA.y, off, 64);
            accA.z += __shfl_xor(accA.z, off, 64);
            accA.w += __shfl_xor(accA.w, off, 64);
            accB.x += __shfl_xor(accB.x, off, 64);
            accB.y += __shfl_xor(accB.y, off, 64);
            accB.z += __shfl_xor(accB.z, off, 64);
            accB.w += __shfl_xor(accB.w, off, 64);
        }
        // per-head normalization BEFORE head-mean exchange
        accA.x *= inv; accA.y *= inv; accA.z *= inv; accA.w *= inv;
        accB.x *= inv; accB.y *= inv; accB.z *= inv; accB.w *= inv;
        // head mean (xor 32 crosses the head boundary)
        accA.x += __shfl_xor(accA.x, 32, 64);
        accA.y += __shfl_xor(accA.y, 32, 64);
        accA.z += __shfl_xor(accA.z, 32, 64);
        accA.w += __shfl_xor(accA.w, 32, 64);
        accB.x += __shfl_xor(accB.x, 32, 64);
        accB.y += __shfl_xor(accB.y, 32, 64);
        accB.z += __shfl_xor(accB.z, 32, 64);
        accB.w += __shfl_xor(accB.w, 32, 64);

        if (lane < 8) {
            uint4 up;
            up.x = pack2(fmaxf(accA.x * 0.5f + bb0.x, 0.f),
                         fmaxf(accA.y * 0.5f + bb0.y, 0.f));
            up.y = pack2(fmaxf(accA.z * 0.5f + bb0.z, 0.f),
                         fmaxf(accA.w * 0.5f + bb0.w, 0.f));
            up.z = pack2(fmaxf(accB.x * 0.5f + bb1.x, 0.f),
                         fmaxf(accB.y * 0.5f + bb1.y, 0.f));
            up.w = pack2(fmaxf(accB.z * 0.5f + bb1.z, 0.f),
                         fmaxf(accB.w * 0.5f + bb1.w, 0.f));
            ((uint4*)hout)[(size_t)n * 8 + c8] = up;
        }
    }
}

// ============================================================================
// Final MLP, block-tile GEMM: 64 nodes/block, 256 threads, 4x4 micro-tile.
// h2 input is fp16. Kept SEPARATE from k_ag (see R14 note).
// ============================================================================
__global__ __launch_bounds__(256)
void k_final(const __half* __restrict__ h2, const float* __restrict__ cpre,
             const int* __restrict__ batch, const float* __restrict__ Wm1,
             const float* __restrict__ Wm2, const float* __restrict__ bm2,
             float* __restrict__ out, int N) {
    __shared__ float zs[64 * 65];
    __shared__ float ws[64 * 64];
    __shared__ float4 w2l[64];
    const int n0 = blockIdx.x * 64;
    const int t = threadIdx.x;

    for (int i = t; i < 1024; i += 256) ((float4*)ws)[i] = ((const float4*)Wm1)[i];
    if (t < 64) w2l[t] = ((const float4*)Wm2)[t];
    for (int i = t; i < 64 * 8; i += 256) {
        int n = i >> 3, k8 = i & 7;
        int gn = n0 + n;
        uint4 v = make_uint4(0u, 0u, 0u, 0u);
        if (gn < N) v = ((const uint4*)h2)[(size_t)gn * 8 + k8];
        float2 f0 = h2f(v.x), f1 = h2f(v.y), f2 = h2f(v.z), f3 = h2f(v.w);
        float* zr = zs + n * 65 + k8 * 8;
        zr[0] = f0.x; zr[1] = f0.y; zr[2] = f1.x; zr[3] = f1.y;
        zr[4] = f2.x; zr[5] = f2.y; zr[6] = f3.x; zr[7] = f3.y;
    }
    __syncthreads();

    const int tx = t & 15, ty = t >> 4;
    const int c0 = tx * 4;
    float acc[4][4];
    #pragma unroll
    for (int i = 0; i < 4; ++i)
        #pragma unroll
        for (int j = 0; j < 4; ++j) acc[i][j] = 0.f;

    for (int k = 0; k < 64; ++k) {
        float4 wv = *(const float4*)(ws + k * 64 + c0);
        #pragma unroll
        for (int i = 0; i < 4; ++i) {
            float zv = zs[(ty * 4 + i) * 65 + k];
            acc[i][0] += zv * wv.x; acc[i][1] += zv * wv.y;
            acc[i][2] += zv * wv.z; acc[i][3] += zv * wv.w;
        }
    }
    __syncthreads();

    float4 wa = w2l[c0], wb = w2l[c0 + 1], wc = w2l[c0 + 2], wd = w2l[c0 + 3];
    #pragma unroll
    for (int i = 0; i < 4; ++i) {
        int nl = ty * 4 + i, gn = n0 + nl;
        float4 o = make_float4(0.f, 0.f, 0.f, 0.f);
        if (gn < N) {
            int b = batch[gn];
            float4 cp = *(const float4*)(cpre + (size_t)b * 64 + c0);
            float m0 = fmaxf(acc[i][0] + cp.x, 0.f);
            float m1 = fmaxf(acc[i][1] + cp.y, 0.f);
            float m2 = fmaxf(acc[i][2] + cp.z, 0.f);
            float m3 = fmaxf(acc[i][3] + cp.w, 0.f);
            o.x = m0 * wa.x + m1 * wb.x + m2 * wc.x + m3 * wd.x;
            o.y = m0 * wa.y + m1 * wb.y + m2 * wc.y + m3 * wd.y;
            o.z = m0 * wa.z + m1 * wb.z + m2 * wc.z + m3 * wd.z;
            o.w = m0 * wa.w + m1 * wb.w + m2 * wc.w + m3 * wd.w;
        }
        *(float4*)(zs + tx * 260 + nl * 4) = o;
    }
    __syncthreads();
    {
        int nl = t >> 2, j = t & 3, gn = n0 + nl;
        float s = 0.f;
        #pragma unroll
        for (int tx2 = 0; tx2 < 16; ++tx2) s += zs[tx2 * 260 + nl * 4 + j];
        if (gn < N) out[(size_t)gn * 4 + j] = s + bm2[j];
    }
}

extern "C" void kernel_launch(void* const* d_in, const int* in_sizes, int n_in,
                              void* d_out, int out_size, void* d_ws, size_t ws_size,
                              hipStream_t stream) {
    const float* x       = (const float*)d_in[0];
    const int*   ei      = (const int*)  d_in[1];
    const int*   batch   = (const int*)  d_in[2];
    const float* climber = (const float*)d_in[3];
    const float* W1  = (const float*)d_in[4];
    const float* as1 = (const float*)d_in[5];
    const float* ad1 = (const float*)d_in[6];
    const float* b1  = (const float*)d_in[7];
    const float* W2  = (const float*)d_in[8];
    const float* as2 = (const float*)d_in[9];
    const float* ad2 = (const float*)d_in[10];
    const float* b2  = (const float*)d_in[11];
    const float* Wc  = (const float*)d_in[12];
    const float* bc  = (const float*)d_in[13];
    const float* Wm1 = (const float*)d_in[14];
    const float* bm1 = (const float*)d_in[15];
    const float* Wm2 = (const float*)d_in[16];
    const float* bm2 = (const float*)d_in[17];

    const int N  = in_sizes[0] / 6;
    const int E  = in_sizes[1] / 2;
    const int G  = in_sizes[3] / 4;

    const int* srcI = ei;
    const int* dstI = ei + E;

    // ---------------- workspace carve ----------------
    char* base = (char*)d_ws;
    size_t off = 0;
    auto carve = [&](size_t bytes) { void* p = base + off; off += (bytes + 255) & ~size_t(255); return p; };
    __half* xph   = (__half*)carve((size_t)N * 128 * 2);
    __half* hbuf  = (__half*)carve((size_t)N * 64 * 2);
    float* asrc   = (float*)carve((size_t)N * 2 * 4);
    float* adst   = (float*)carve((size_t)N * 2 * 4);
    float* cpre   = (float*)carve((size_t)G * 64 * 4);
    int*   deg    = (int*)  carve((size_t)N * 4);
    int*   rowptr = (int*)  carve((size_t)(N + 1) * 4);
    int*   cur    = (int*)  carve((size_t)N * 4);
    int*   partial= (int*)  carve(4096 * 4);
    int*   csr_src= (int*)  carve((size_t)E * 4);

    const int tpb = 256;
    const int nScanBlk = (N + 1023) / 1024;
    const int nEdgeBlk = (E + tpb - 1) / tpb;
    const int nClimber = (G + 3) / 4;
    const int PG = 2048;
    const int nTile = (N + 63) / 64;

    // ---------------- pre: gemm6 + hist + climber (fused, independent) ----
    hipMemsetAsync(deg, 0, (size_t)N * 4, stream);
    k_pre<<<nTile + nEdgeBlk + nClimber, tpb, 0, stream>>>(
        x, W1, as1, ad1, xph, asrc, adst, N,
        dstI, deg, E,
        climber, Wc, bc, Wm1, bm1, cpre, G, nTile, nEdgeBlk);

    // ---------------- CSR finalize ----------------
    k_scan_partial<<<nScanBlk, tpb, 0, stream>>>(deg, partial, N);
    k_scan_final<<<nScanBlk, tpb, 0, stream>>>(deg, partial, rowptr, cur, N, E, nScanBlk);
    k_scatter_cur<<<nEdgeBlk, tpb, 0, stream>>>(srcI, dstI, cur, csr_src, E);

    // ---------------- layer 1 aggregate ----------------
    k_ag<<<PG, tpb, 0, stream>>>(rowptr, csr_src, asrc, adst, xph, b1, hbuf, N);

    // ---------------- layer 2 ----------------
    k_xp_gemm64h<<<nTile, tpb, 0, stream>>>(hbuf, W2, as2, ad2, xph, asrc, adst, N);
    k_ag<<<PG, tpb, 0, stream>>>(rowptr, csr_src, asrc, adst, xph, b2, hbuf, N);

    // ---------------- classifier ----------------
    k_final<<<nTile, tpb, 0, stream>>>(hbuf, cpre, batch, Wm1, Wm2, bm2, (float*)d_out, N);
}

// Round 6
// 314.596 us; speedup vs baseline: 1.1450x; 1.1450x over previous
//
#include <hip/hip_runtime.h>
#include <hip/hip_fp16.h>

#define SLOPE 0.2f

__device__ __forceinline__ float lrelu(float v) { return v >= 0.f ? v : SLOPE * v; }

__device__ __forceinline__ unsigned pack2(float a, float b) {
    __half2 h = __floats2half2_rn(a, b);
    return *reinterpret_cast<unsigned*>(&h);
}
__device__ __forceinline__ float2 h2f(unsigned u) {
    __half2 h = *reinterpret_cast<__half2*>(&u);
    return __half22float2(h);
}

// 8 half elements (uint4) scaled by f32 'a', accumulated into 8 f32 lanes.
// v_fma_mix_f32 folds the f16->f32 convert into the FMA.
__device__ __forceinline__ void mix8(float4& A, float4& B, float a, uint4 u) {
    asm("v_fma_mix_f32 %0, %8, %12, %0 op_sel:[0,0,0] op_sel_hi:[1,0,0]\n\t"
        "v_fma_mix_f32 %1, %8, %12, %1 op_sel:[1,0,0] op_sel_hi:[1,0,0]\n\t"
        "v_fma_mix_f32 %2, %9, %12, %2 op_sel:[0,0,0] op_sel_hi:[1,0,0]\n\t"
        "v_fma_mix_f32 %3, %9, %12, %3 op_sel:[1,0,0] op_sel_hi:[1,0,0]\n\t"
        "v_fma_mix_f32 %4, %10, %12, %4 op_sel:[0,0,0] op_sel_hi:[1,0,0]\n\t"
        "v_fma_mix_f32 %5, %10, %12, %5 op_sel:[1,0,0] op_sel_hi:[1,0,0]\n\t"
        "v_fma_mix_f32 %6, %11, %12, %6 op_sel:[0,0,0] op_sel_hi:[1,0,0]\n\t"
        "v_fma_mix_f32 %7, %11, %12, %7 op_sel:[1,0,0] op_sel_hi:[1,0,0]"
        : "+v"(A.x), "+v"(A.y), "+v"(A.z), "+v"(A.w),
          "+v"(B.x), "+v"(B.y), "+v"(B.z), "+v"(B.w)
        : "v"(u.x), "v"(u.y), "v"(u.z), "v"(u.w), "v"(a));
}

// ============================================================================
// xp = h @ W (64 -> 128 = 2 heads * 64) + attention dots, block-tile GEMM.
// Input h is fp16 (written by k_ag). 64 nodes/block, 256 threads.
// ============================================================================
__global__ __launch_bounds__(256)
void k_xp_gemm64h(const __half* __restrict__ x, const float* __restrict__ W,
                  const float* __restrict__ as_, const float* __restrict__ ad_,
                  __half* __restrict__ xph, float* __restrict__ asrc,
                  float* __restrict__ adst, int N) {
    constexpr int K = 64;
    constexpr int ZS = K + 1;
    __shared__ float zs[64 * ZS];
    __shared__ float ws[K * 128];
    const int n0 = blockIdx.x * 64;
    const int t = threadIdx.x;

    for (int i = t; i < K * 32; i += 256) ((float4*)ws)[i] = ((const float4*)W)[i];
    for (int i = t; i < 64 * 8; i += 256) {          // 8 x uint4 (8 halfs) per row
        int n = i >> 3, k8 = i & 7;
        int gn = n0 + n;
        uint4 v = make_uint4(0u, 0u, 0u, 0u);
        if (gn < N) v = ((const uint4*)x)[(size_t)gn * 8 + k8];
        float2 f0 = h2f(v.x), f1 = h2f(v.y), f2 = h2f(v.z), f3 = h2f(v.w);
        float* zr = zs + n * ZS + k8 * 8;
        zr[0] = f0.x; zr[1] = f0.y; zr[2] = f1.x; zr[3] = f1.y;
        zr[4] = f2.x; zr[5] = f2.y; zr[6] = f3.x; zr[7] = f3.y;
    }
    __syncthreads();

    const int tx = t & 15, ty = t >> 4;
    const int c0a = tx * 4;
    const int c0b = 64 + tx * 4;

    float4 asA = *(const float4*)(as_ + c0a);
    float4 asB = *(const float4*)(as_ + c0b);
    float4 adA = *(const float4*)(ad_ + c0a);
    float4 adB = *(const float4*)(ad_ + c0b);

    float acc[4][8];
    #pragma unroll
    for (int i = 0; i < 4; ++i)
        #pragma unroll
        for (int j = 0; j < 8; ++j) acc[i][j] = 0.f;

    for (int k = 0; k < K; ++k) {
        float4 w0 = *(const float4*)(ws + k * 128 + c0a);
        float4 w1 = *(const float4*)(ws + k * 128 + c0b);
        #pragma unroll
        for (int i = 0; i < 4; ++i) {
            float zv = zs[(ty * 4 + i) * ZS + k];
            acc[i][0] += zv * w0.x; acc[i][1] += zv * w0.y;
            acc[i][2] += zv * w0.z; acc[i][3] += zv * w0.w;
            acc[i][4] += zv * w1.x; acc[i][5] += zv * w1.y;
            acc[i][6] += zv * w1.z; acc[i][7] += zv * w1.w;
        }
    }

    #pragma unroll
    for (int i = 0; i < 4; ++i) {
        int nl = ty * 4 + i, gn = n0 + nl;
        if (gn < N) {
            uint2 ua, ub;
            ua.x = pack2(acc[i][0], acc[i][1]);
            ua.y = pack2(acc[i][2], acc[i][3]);
            ub.x = pack2(acc[i][4], acc[i][5]);
            ub.y = pack2(acc[i][6], acc[i][7]);
            *(uint2*)(xph + (size_t)gn * 128 + c0a) = ua;
            *(uint2*)(xph + (size_t)gn * 128 + c0b) = ub;
        }
        float ps0 = acc[i][0]*asA.x + acc[i][1]*asA.y + acc[i][2]*asA.z + acc[i][3]*asA.w;
        float ps1 = acc[i][4]*asB.x + acc[i][5]*asB.y + acc[i][6]*asB.z + acc[i][7]*asB.w;
        float pd0 = acc[i][0]*adA.x + acc[i][1]*adA.y + acc[i][2]*adA.z + acc[i][3]*adA.w;
        float pd1 = acc[i][4]*adB.x + acc[i][5]*adB.y + acc[i][6]*adB.z + acc[i][7]*adB.w;
        #pragma unroll
        for (int off = 1; off <= 8; off <<= 1) {
            ps0 += __shfl_xor(ps0, off, 64);
            ps1 += __shfl_xor(ps1, off, 64);
            pd0 += __shfl_xor(pd0, off, 64);
            pd1 += __shfl_xor(pd1, off, 64);
        }
        if (tx == 0 && gn < N) {
            asrc[gn * 2]     = ps0;
            asrc[gn * 2 + 1] = ps1;
            adst[gn * 2]     = pd0;
            adst[gn * 2 + 1] = pd1;
        }
    }
}

// ============================================================================
// CSR build: histogram with rank capture, ILP-4 (R19).
// Each thread owns 4 edges: int4 loads, 4 independent atomic round-trips in
// flight (this kernel is latency-bound: VALUBusy ~0.3%, HBM ~13%).
// NOTE (R18): cursor-based scatter (atomic->dependent store) is 74us — never
// couple the scatter store to an atomic result.
// ============================================================================
__global__ void k_hist(const int* __restrict__ dst, int* __restrict__ deg,
                       int* __restrict__ rank, int E) {
    int e0 = (blockIdx.x * blockDim.x + threadIdx.x) * 4;
    if (e0 + 3 < E) {
        int4 d = *(const int4*)(dst + e0);
        int r0 = atomicAdd(&deg[d.x], 1);
        int r1 = atomicAdd(&deg[d.y], 1);
        int r2 = atomicAdd(&deg[d.z], 1);
        int r3 = atomicAdd(&deg[d.w], 1);
        *(int4*)(rank + e0) = make_int4(r0, r1, r2, r3);
    } else {
        for (int e = e0; e < E; ++e) rank[e] = atomicAdd(&deg[dst[e]], 1);
    }
}

__global__ void k_scan_partial(const int* __restrict__ deg, int* __restrict__ partial, int N) {
    int b = blockIdx.x, t = threadIdx.x;
    int base = b * 1024 + t * 4;
    int s = 0;
    for (int i = 0; i < 4; ++i) { int idx = base + i; if (idx < N) s += deg[idx]; }
    __shared__ int sh[256];
    sh[t] = s; __syncthreads();
    for (int off = 128; off > 0; off >>= 1) { if (t < off) sh[t] += sh[t + off]; __syncthreads(); }
    if (t == 0) partial[b] = sh[0];
}

__global__ void k_scan_final(const int* __restrict__ deg, const int* __restrict__ partial,
                             int* __restrict__ rowptr, int N, int E, int nb) {
    int b = blockIdx.x, t = threadIdx.x;
    __shared__ int shp[256];
    shp[t] = (t < nb) ? partial[t] : 0;
    __syncthreads();
    for (int off = 1; off < 256; off <<= 1) {
        int v = (t >= off) ? shp[t - off] : 0;
        __syncthreads();
        shp[t] += v;
        __syncthreads();
    }
    int pbase = (b > 0) ? shp[b - 1] : 0;
    __syncthreads();

    int base = b * 1024 + t * 4;
    int local[4]; int s = 0;
    for (int i = 0; i < 4; ++i) { int idx = base + i; local[i] = (idx < N) ? deg[idx] : 0; s += local[i]; }
    __shared__ int sh[256];
    int orig = s;
    sh[t] = s; __syncthreads();
    for (int off = 1; off < 256; off <<= 1) {
        int v = (t >= off) ? sh[t - off] : 0;
        __syncthreads();
        sh[t] += v;
        __syncthreads();
    }
    int run = pbase + sh[t] - orig;
    for (int i = 0; i < 4; ++i) {
        int idx = base + i;
        if (idx < N) rowptr[idx] = run;
        run += local[i];
    }
    if (b == 0 && t == 0) rowptr[N] = E;
}

// ============================================================================
// FUSED independent work after scan_final, branched on blockIdx range:
//   [0, nEdgeBlk4)               -> csr scatter, ILP-4 (rank-based, R19)
//   [nEdgeBlk4, +nTile)          -> xp_gemm K=6 (layer-1 projection)
//   [.., +nClimber)              -> climber embed + cpre
// Scatter overlaps with the projection GEMM (R4 structure, 318us baseline).
// ============================================================================
__global__ __launch_bounds__(256)
void k_fused3(const int* __restrict__ srcI, const int* __restrict__ dstI,
              const int* __restrict__ rowptr, const int* __restrict__ rank,
              int* __restrict__ csr_src, int E,
              const float* __restrict__ x, const float* __restrict__ W1,
              const float* __restrict__ as1, const float* __restrict__ ad1,
              __half* __restrict__ xph, float* __restrict__ asrc,
              float* __restrict__ adst, int N,
              const float* __restrict__ climber, const float* __restrict__ Wc,
              const float* __restrict__ bc, const float* __restrict__ Wm1,
              const float* __restrict__ bm1, float* __restrict__ cpre, int G,
              int nEdgeBlk4, int nTile) {
    __shared__ float smem[4352];        // max(climber 4352, gemm6 1216) floats
    int bid = blockIdx.x;
    const int t = threadIdx.x;

    if (bid < nEdgeBlk4) {
        // ---- csr scatter, 4 edges/thread: independent gathers + stores ----
        int e0 = (bid * 256 + t) * 4;
        if (e0 + 3 < E) {
            int4 s = *(const int4*)(srcI + e0);
            int4 d = *(const int4*)(dstI + e0);
            int4 r = *(const int4*)(rank + e0);
            int p0 = rowptr[d.x] + r.x;
            int p1 = rowptr[d.y] + r.y;
            int p2 = rowptr[d.z] + r.z;
            int p3 = rowptr[d.w] + r.w;
            csr_src[p0] = s.x;
            csr_src[p1] = s.y;
            csr_src[p2] = s.z;
            csr_src[p3] = s.w;
        } else {
            for (int e = e0; e < E; ++e)
                csr_src[rowptr[dstI[e]] + rank[e]] = srcI[e];
        }
        return;
    }
    bid -= nEdgeBlk4;
    if (bid < nTile) {
        // ---- xp_gemm K=6 ----
        constexpr int K = 6, ZS = 7;
        float* zs = smem;               // 64*7  = 448
        float* ws = smem + 448;         // 6*128 = 768 (offset 1792 B, 16B-aligned)
        const int n0 = bid * 64;

        for (int i = t; i < K * 32; i += 256) ((float4*)ws)[i] = ((const float4*)W1)[i];
        for (int i = t; i < 64 * K; i += 256) {
            int n = i / K, k = i - n * K;
            int gn = n0 + n;
            zs[n * ZS + k] = (gn < N) ? x[(size_t)gn * K + k] : 0.f;
        }
        __syncthreads();

        const int tx = t & 15, ty = t >> 4;
        const int c0a = tx * 4;
        const int c0b = 64 + tx * 4;

        float4 asA = *(const float4*)(as1 + c0a);
        float4 asB = *(const float4*)(as1 + c0b);
        float4 adA = *(const float4*)(ad1 + c0a);
        float4 adB = *(const float4*)(ad1 + c0b);

        float acc[4][8];
        #pragma unroll
        for (int i = 0; i < 4; ++i)
            #pragma unroll
            for (int j = 0; j < 8; ++j) acc[i][j] = 0.f;

        for (int k = 0; k < K; ++k) {
            float4 w0 = *(const float4*)(ws + k * 128 + c0a);
            float4 w1 = *(const float4*)(ws + k * 128 + c0b);
            #pragma unroll
            for (int i = 0; i < 4; ++i) {
                float zv = zs[(ty * 4 + i) * ZS + k];
                acc[i][0] += zv * w0.x; acc[i][1] += zv * w0.y;
                acc[i][2] += zv * w0.z; acc[i][3] += zv * w0.w;
                acc[i][4] += zv * w1.x; acc[i][5] += zv * w1.y;
                acc[i][6] += zv * w1.z; acc[i][7] += zv * w1.w;
            }
        }

        #pragma unroll
        for (int i = 0; i < 4; ++i) {
            int nl = ty * 4 + i, gn = n0 + nl;
            if (gn < N) {
                uint2 ua, ub;
                ua.x = pack2(acc[i][0], acc[i][1]);
                ua.y = pack2(acc[i][2], acc[i][3]);
                ub.x = pack2(acc[i][4], acc[i][5]);
                ub.y = pack2(acc[i][6], acc[i][7]);
                *(uint2*)(xph + (size_t)gn * 128 + c0a) = ua;
                *(uint2*)(xph + (size_t)gn * 128 + c0b) = ub;
            }
            float ps0 = acc[i][0]*asA.x + acc[i][1]*asA.y + acc[i][2]*asA.z + acc[i][3]*asA.w;
            float ps1 = acc[i][4]*asB.x + acc[i][5]*asB.y + acc[i][6]*asB.z + acc[i][7]*asB.w;
            float pd0 = acc[i][0]*adA.x + acc[i][1]*adA.y + acc[i][2]*adA.z + acc[i][3]*adA.w;
            float pd1 = acc[i][4]*adB.x + acc[i][5]*adB.y + acc[i][6]*adB.z + acc[i][7]*adB.w;
            #pragma unroll
            for (int off = 1; off <= 8; off <<= 1) {
                ps0 += __shfl_xor(ps0, off, 64);
                ps1 += __shfl_xor(ps1, off, 64);
                pd0 += __shfl_xor(pd0, off, 64);
                pd1 += __shfl_xor(pd1, off, 64);
            }
            if (tx == 0 && gn < N) {
                asrc[gn * 2]     = ps0;
                asrc[gn * 2 + 1] = ps1;
                adst[gn * 2]     = pd0;
                adst[gn * 2 + 1] = pd1;
            }
        }
        return;
    }
    bid -= nTile;
    {
        // ---- climber embed + cpre ----
        float* ce   = smem;             // 4*64
        float* wm1b = smem + 256;       // 64*64
        for (int i = t; i < 1024; i += 256) ((float4*)wm1b)[i] = ((const float4*)Wm1)[1024 + i];
        int gl = t >> 6, c = t & 63;
        int g = bid * 4 + gl;
        float acc = bc[c];
        if (g < G)
            for (int k = 0; k < 4; ++k) acc += climber[g * 4 + k] * Wc[k * 64 + c];
        ce[gl * 64 + c] = fmaxf(acc, 0.f);
        __syncthreads();
        float o = bm1[c];
        for (int k = 0; k < 64; ++k) o += ce[gl * 64 + k] * wm1b[k * 64 + c];
        if (g < G) cpre[(size_t)g * 64 + c] = o;
    }
}

// ============================================================================
// FUSED softmax + gather (R1 structure — strided node walk, known-good):
// v_fma_mix gathers, 4-slot uniform tail, deferred normalization, fp16 out.
// NOTE (R14): do NOT fuse the classifier MLP in here (occupancy collapse).
// NOTE (R16): do NOT switch to contiguous chunks + deep pipeline (56->76us).
// NOTE (R4): write-byte cuts don't speed this kernel; it is gather/issue-bound.
// ============================================================================
__global__ void k_ag(const int* __restrict__ rowptr, const int* __restrict__ csr_src,
                     const float* __restrict__ asrc, const float* __restrict__ adst,
                     const __half* __restrict__ xph, const float* __restrict__ b,
                     __half* __restrict__ hout, int N) {
    int tid = blockIdx.x * blockDim.x + threadIdx.x;
    int lane = threadIdx.x & 63;
    int wid = tid >> 6;
    int nw = (gridDim.x * blockDim.x) >> 6;
    const int l  = lane & 31;
    const int hh = lane >> 5;
    const int g4 = (lane >> 3) & 3;
    const int c8 = lane & 7;
    const int lofs = hh * 8 + c8;
    const uint4* xp4 = (const uint4*)xph;
    float4 bb0 = ((const float4*)b)[c8 * 2];
    float4 bb1 = ((const float4*)b)[c8 * 2 + 1];

    for (int n = wid; n < N; n += nw) {
        int rs = rowptr[n], re = rowptr[n + 1], cnt = re - rs;
        uint4 uself = xp4[(size_t)n * 16 + lofs];       // issue early; 2 lines/wave
        float a_dst = adst[n * 2 + hh];
        float eself = __expf(lrelu(asrc[n * 2 + hh] + a_dst));

        float4 accA = make_float4(0.f, 0.f, 0.f, 0.f);
        float4 accB = make_float4(0.f, 0.f, 0.f, 0.f);
        float den;

        if (cnt <= 32) {
            float ev = 0.f; int s_reg = n;
            if (l < cnt) {
                s_reg = csr_src[rs + l];
                ev = __expf(lrelu(asrc[s_reg * 2 + hh] + a_dst));
            }
            if (g4 == 0) mix8(accA, accB, eself, uself);

            const int base = (hh << 5) - rs;
            int e0 = rs;
            for (; e0 + 4 < re; e0 += 8) {
                int ea = e0 + g4, eb = e0 + 4 + g4;
                float aa = __shfl(ev,    base + ea, 64);   // ea < re guaranteed
                int   sa = __shfl(s_reg, base + ea, 64);
                float ab = __shfl(ev,    base + eb, 64);
                int   sb = __shfl(s_reg, base + eb, 64);
                if (eb >= re) { ab = 0.f; sb = n; }
                uint4 u1 = xp4[(size_t)sa * 16 + lofs];
                uint4 u2 = xp4[(size_t)sb * 16 + lofs];
                mix8(accA, accB, aa, u1);
                mix8(accA, accB, ab, u2);
            }
            if (e0 < re) {                                  // wave-uniform 4-slot tail
                int ea = e0 + g4;
                float aa = __shfl(ev,    base + ea, 64);
                int   sa = __shfl(s_reg, base + ea, 64);
                if (ea >= re) { aa = 0.f; sa = n; }
                uint4 u1 = xp4[(size_t)sa * 16 + lofs];
                mix8(accA, accB, aa, u1);
            }
            // den reduce after gathers: shfls (LDS pipe) overlap vmcnt waits
            den = ev + (l == 0 ? eself : 0.f);
            #pragma unroll
            for (int off = 16; off > 0; off >>= 1) den += __shfl_xor(den, off, 64);
        } else {
            den = (l == 0) ? eself : 0.f;
            for (int e = rs + l; e < re; e += 32)
                den += __expf(lrelu(asrc[csr_src[e] * 2 + hh] + a_dst));
            #pragma unroll
            for (int off = 16; off > 0; off >>= 1) den += __shfl_xor(den, off, 64);
            if (g4 == 0) mix8(accA, accB, eself, uself);
            for (int e0 = rs; e0 < re; e0 += 8) {
                int ea = e0 + g4, eb = e0 + 4 + g4;
                bool va = ea < re, vb = eb < re;
                int sa = va ? csr_src[ea] : n;
                int sb = vb ? csr_src[eb] : n;
                float aa = va ? __expf(lrelu(asrc[sa * 2 + hh] + a_dst)) : 0.f;
                float ab = vb ? __expf(lrelu(asrc[sb * 2 + hh] + a_dst)) : 0.f;
                uint4 u1 = xp4[(size_t)sa * 16 + lofs];
                uint4 u2 = xp4[(size_t)sb * 16 + lofs];
                mix8(accA, accB, aa, u1);
                mix8(accA, accB, ab, u2);
            }
        }

        float inv = 1.f / (den + 1e-16f);

        // slot-group reduce (within head)
        #pragma unroll
        for (int off = 8; off <= 16; off <<= 1) {
            accA.x += __shfl_xor(accA.x, off, 64);
            accA.y += __shfl_xor(accA.y, off, 64);
            accA.z += __shfl_xor(accA.z, off, 64);
            accA.w += __shfl_xor(accA.w, off, 64);
            accB.x += __shfl_xor(accB.x, off, 64);
            accB.y += __shfl_xor(accB.y, off, 64);
            accB.z += __shfl_xor(accB.z, off, 64);
            accB.w += __shfl_xor(accB.w, off, 64);
        }
        // per-head normalization BEFORE head-mean exchange
        accA.x *= inv; accA.y *= inv; accA.z *= inv; accA.w *= inv;
        accB.x *= inv; accB.y *= inv; accB.z *= inv; accB.w *= inv;
        // head mean (xor 32 crosses the head boundary)
        accA.x += __shfl_xor(accA.x, 32, 64);
        accA.y += __shfl_xor(accA.y, 32, 64);
        accA.z += __shfl_xor(accA.z, 32, 64);
        accA.w += __shfl_xor(accA.w, 32, 64);
        accB.x += __shfl_xor(accB.x, 32, 64);
        accB.y += __shfl_xor(accB.y, 32, 64);
        accB.z += __shfl_xor(accB.z, 32, 64);
        accB.w += __shfl_xor(accB.w, 32, 64);

        if (lane < 8) {
            uint4 up;
            up.x = pack2(fmaxf(accA.x * 0.5f + bb0.x, 0.f),
                         fmaxf(accA.y * 0.5f + bb0.y, 0.f));
            up.y = pack2(fmaxf(accA.z * 0.5f + bb0.z, 0.f),
                         fmaxf(accA.w * 0.5f + bb0.w, 0.f));
            up.z = pack2(fmaxf(accB.x * 0.5f + bb1.x, 0.f),
                         fmaxf(accB.y * 0.5f + bb1.y, 0.f));
            up.w = pack2(fmaxf(accB.z * 0.5f + bb1.z, 0.f),
                         fmaxf(accB.w * 0.5f + bb1.w, 0.f));
            ((uint4*)hout)[(size_t)n * 8 + c8] = up;
        }
    }
}

// ============================================================================
// Final MLP, block-tile GEMM: 64 nodes/block, 256 threads, 4x4 micro-tile.
// h2 input is fp16. Kept SEPARATE from k_ag (see R14 note).
// ============================================================================
__global__ __launch_bounds__(256)
void k_final(const __half* __restrict__ h2, const float* __restrict__ cpre,
             const int* __restrict__ batch, const float* __restrict__ Wm1,
             const float* __restrict__ Wm2, const float* __restrict__ bm2,
             float* __restrict__ out, int N) {
    __shared__ float zs[64 * 65];
    __shared__ float ws[64 * 64];
    __shared__ float4 w2l[64];
    const int n0 = blockIdx.x * 64;
    const int t = threadIdx.x;

    for (int i = t; i < 1024; i += 256) ((float4*)ws)[i] = ((const float4*)Wm1)[i];
    if (t < 64) w2l[t] = ((const float4*)Wm2)[t];
    for (int i = t; i < 64 * 8; i += 256) {
        int n = i >> 3, k8 = i & 7;
        int gn = n0 + n;
        uint4 v = make_uint4(0u, 0u, 0u, 0u);
        if (gn < N) v = ((const uint4*)h2)[(size_t)gn * 8 + k8];
        float2 f0 = h2f(v.x), f1 = h2f(v.y), f2 = h2f(v.z), f3 = h2f(v.w);
        float* zr = zs + n * 65 + k8 * 8;
        zr[0] = f0.x; zr[1] = f0.y; zr[2] = f1.x; zr[3] = f1.y;
        zr[4] = f2.x; zr[5] = f2.y; zr[6] = f3.x; zr[7] = f3.y;
    }
    __syncthreads();

    const int tx = t & 15, ty = t >> 4;
    const int c0 = tx * 4;
    float acc[4][4];
    #pragma unroll
    for (int i = 0; i < 4; ++i)
        #pragma unroll
        for (int j = 0; j < 4; ++j) acc[i][j] = 0.f;

    for (int k = 0; k < 64; ++k) {
        float4 wv = *(const float4*)(ws + k * 64 + c0);
        #pragma unroll
        for (int i = 0; i < 4; ++i) {
            float zv = zs[(ty * 4 + i) * 65 + k];
            acc[i][0] += zv * wv.x; acc[i][1] += zv * wv.y;
            acc[i][2] += zv * wv.z; acc[i][3] += zv * wv.w;
        }
    }
    __syncthreads();

    float4 wa = w2l[c0], wb = w2l[c0 + 1], wc = w2l[c0 + 2], wd = w2l[c0 + 3];
    #pragma unroll
    for (int i = 0; i < 4; ++i) {
        int nl = ty * 4 + i, gn = n0 + nl;
        float4 o = make_float4(0.f, 0.f, 0.f, 0.f);
        if (gn < N) {
            int b = batch[gn];
            float4 cp = *(const float4*)(cpre + (size_t)b * 64 + c0);
            float m0 = fmaxf(acc[i][0] + cp.x, 0.f);
            float m1 = fmaxf(acc[i][1] + cp.y, 0.f);
            float m2 = fmaxf(acc[i][2] + cp.z, 0.f);
            float m3 = fmaxf(acc[i][3] + cp.w, 0.f);
            o.x = m0 * wa.x + m1 * wb.x + m2 * wc.x + m3 * wd.x;
            o.y = m0 * wa.y + m1 * wb.y + m2 * wc.y + m3 * wd.y;
            o.z = m0 * wa.z + m1 * wb.z + m2 * wc.z + m3 * wd.z;
            o.w = m0 * wa.w + m1 * wb.w + m2 * wc.w + m3 * wd.w;
        }
        *(float4*)(zs + tx * 260 + nl * 4) = o;
    }
    __syncthreads();
    {
        int nl = t >> 2, j = t & 3, gn = n0 + nl;
        float s = 0.f;
        #pragma unroll
        for (int tx2 = 0; tx2 < 16; ++tx2) s += zs[tx2 * 260 + nl * 4 + j];
        if (gn < N) out[(size_t)gn * 4 + j] = s + bm2[j];
    }
}

extern "C" void kernel_launch(void* const* d_in, const int* in_sizes, int n_in,
                              void* d_out, int out_size, void* d_ws, size_t ws_size,
                              hipStream_t stream) {
    const float* x       = (const float*)d_in[0];
    const int*   ei      = (const int*)  d_in[1];
    const int*   batch   = (const int*)  d_in[2];
    const float* climber = (const float*)d_in[3];
    const float* W1  = (const float*)d_in[4];
    const float* as1 = (const float*)d_in[5];
    const float* ad1 = (const float*)d_in[6];
    const float* b1  = (const float*)d_in[7];
    const float* W2  = (const float*)d_in[8];
    const float* as2 = (const float*)d_in[9];
    const float* ad2 = (const float*)d_in[10];
    const float* b2  = (const float*)d_in[11];
    const float* Wc  = (const float*)d_in[12];
    const float* bc  = (const float*)d_in[13];
    const float* Wm1 = (const float*)d_in[14];
    const float* bm1 = (const float*)d_in[15];
    const float* Wm2 = (const float*)d_in[16];
    const float* bm2 = (const float*)d_in[17];

    const int N  = in_sizes[0] / 6;
    const int E  = in_sizes[1] / 2;
    const int G  = in_sizes[3] / 4;

    const int* srcI = ei;
    const int* dstI = ei + E;

    // ---------------- workspace carve ----------------
    char* base = (char*)d_ws;
    size_t off = 0;
    auto carve = [&](size_t bytes) { void* p = base + off; off += (bytes + 255) & ~size_t(255); return p; };
    __half* xph   = (__half*)carve((size_t)N * 128 * 2);
    __half* hbuf  = (__half*)carve((size_t)N * 64 * 2);
    float* asrc   = (float*)carve((size_t)N * 2 * 4);
    float* adst   = (float*)carve((size_t)N * 2 * 4);
    float* cpre   = (float*)carve((size_t)G * 64 * 4);
    int*   deg    = (int*)  carve((size_t)N * 4);
    int*   rowptr = (int*)  carve((size_t)(N + 1) * 4);
    int*   rank   = (int*)  carve((size_t)E * 4);
    int*   partial= (int*)  carve(4096 * 4);
    int*   csr_src= (int*)  carve((size_t)E * 4);

    const int tpb = 256;
    const int nScanBlk = (N + 1023) / 1024;
    const int nEdgeBlk4 = (E + 1023) / 1024;     // 4 edges/thread
    const int nClimber = (G + 3) / 4;
    const int PG = 2048;
    const int nTile = (N + 63) / 64;

    // ---------------- CSR build + layer-1 projection + climber ----------
    hipMemsetAsync(deg, 0, (size_t)N * 4, stream);
    k_hist<<<nEdgeBlk4, tpb, 0, stream>>>(dstI, deg, rank, E);
    k_scan_partial<<<nScanBlk, tpb, 0, stream>>>(deg, partial, N);
    k_scan_final<<<nScanBlk, tpb, 0, stream>>>(deg, partial, rowptr, N, E, nScanBlk);
    k_fused3<<<nEdgeBlk4 + nTile + nClimber, tpb, 0, stream>>>(
        srcI, dstI, rowptr, rank, csr_src, E,
        x, W1, as1, ad1, xph, asrc, adst, N,
        climber, Wc, bc, Wm1, bm1, cpre, G, nEdgeBlk4, nTile);

    // ---------------- layer 1 aggregate ----------------
    k_ag<<<PG, tpb, 0, stream>>>(rowptr, csr_src, asrc, adst, xph, b1, hbuf, N);

    // ---------------- layer 2 ----------------
    k_xp_gemm64h<<<nTile, tpb, 0, stream>>>(hbuf, W2, as2, ad2, xph, asrc, adst, N);
    k_ag<<<PG, tpb, 0, stream>>>(rowptr, csr_src, asrc, adst, xph, b2, hbuf, N);

    // ---------------- classifier ----------------
    k_final<<<nTile, tpb, 0, stream>>>(hbuf, cpre, batch, Wm1, Wm2, bm2, (float*)d_out, N);
}